// Round 5
// baseline (202.883 us; speedup 1.0000x reference)
//
#include <hip/hip_runtime.h>

// B=2, N=2048, DIM=768, HEADS=12, HD=64, SCALE=1/8
#define BATCH 2
#define SEQ   2048
#define DIMC  768
#define HEADS 12
#define HD    64
// Q prescale = attention scale (1/8) * log2(e); flash uses exp2 (v_exp_f32 native)
#define QSCALE 0.1803368801111204f

typedef short bf16x8 __attribute__((ext_vector_type(8)));
typedef float f32x4  __attribute__((ext_vector_type(4)));
typedef float f32x16 __attribute__((ext_vector_type(16)));

__device__ __forceinline__ unsigned short f2bf(float f) {
    union { float f; unsigned int u; } a; a.f = f;
    unsigned int r = a.u + 0x7fffu + ((a.u >> 16) & 1u);
    return (unsigned short)(r >> 16);
}
__device__ __forceinline__ unsigned int pack2bf(float lo, float hi) {
    union { float f; unsigned int u; } a, b; a.f = lo; b.f = hi;
    return __builtin_amdgcn_perm(b.u + 0x8000u, a.u + 0x8000u, 0x07060302);
}
// packed f32x2 -> bf16x2 in ONE VALU op (RNE). No builtin on gfx950 (m240): inline asm.
__device__ __forceinline__ unsigned int cvtpk_bf16(float lo, float hi) {
    unsigned int r;
    asm("v_cvt_pk_bf16_f32 %0, %1, %2" : "=v"(r) : "v"(lo), "v"(hi));
    return r;
}
// 2^x via the native v_exp_f32 (avoid __exp2f: collides with glibc math.h on this toolchain)
__device__ __forceinline__ float exp2f_fast(float x) { return __builtin_amdgcn_exp2f(x); }

// async global->LDS, 16B per lane. LDS dest is wave-uniform base + lane*16.
__device__ __forceinline__ void gload16(const unsigned short* g, unsigned short* l) {
    __builtin_amdgcn_global_load_lds(
        (const __attribute__((address_space(1))) unsigned int*)g,
        (__attribute__((address_space(3))) unsigned int*)l, 16, 0, 0);
}

// ---- prep: weight transposes + x fp32->bf16 (xb needed so QKV GEMM can
// stage A with global_load_lds, which cannot convert). ----
// blocks [0,1248): W [768][N] fp32 -> WT [N][768] bf16 via 32x32 LDS tiles.
// blocks [1248,2784): x -> xb, 2048 elems/block, vectorized.
__global__ void prep(const float* __restrict__ Wq, const float* __restrict__ Wkv,
                     const float* __restrict__ Wproj, const float* __restrict__ x,
                     unsigned short* __restrict__ WqT, unsigned short* __restrict__ WkvT,
                     unsigned short* __restrict__ WprT, unsigned short* __restrict__ xb)
{
    const int bid = blockIdx.x, t = threadIdx.x;
    if (bid >= 1248) {
        const size_t base = (size_t)(bid - 1248) * 2048 + (size_t)t * 8;
        float4 v0 = *(const float4*)&x[base];
        float4 v1 = *(const float4*)&x[base + 4];
        uint4 o = { pack2bf(v0.x, v0.y), pack2bf(v0.z, v0.w),
                    pack2bf(v1.x, v1.y), pack2bf(v1.z, v1.w) };
        *(uint4*)&xb[base] = o;
        return;
    }
    __shared__ float sT[32][33];
    const float* W; unsigned short* WT; int N, tb;
    if (bid < 576)      { W = Wq;    WT = WqT;  N = DIMC;   tb = bid; }
    else if (bid < 672) { W = Wkv;   WT = WkvT; N = 2 * HD; tb = bid - 576; }
    else                { W = Wproj; WT = WprT; N = DIMC;   tb = bid - 672; }
    const int tilesN = N / 32;
    const int k0 = (tb / tilesN) * 32, n0 = (tb - (tb / tilesN) * tilesN) * 32;
    const int r = t >> 3, c4 = (t & 7) * 4;
    float4 v = *(const float4*)&W[(size_t)(k0 + r) * N + n0 + c4];
    sT[c4 + 0][r] = v.x; sT[c4 + 1][r] = v.y; sT[c4 + 2][r] = v.z; sT[c4 + 3][r] = v.w;
    __syncthreads();
    ushort4 o = { f2bf(sT[r][c4]), f2bf(sT[r][c4 + 1]), f2bf(sT[r][c4 + 2]), f2bf(sT[r][c4 + 3]) };
    *(ushort4*)&WT[(size_t)(n0 + r) * 768 + k0 + c4] = o;
}

// ---- GEMM: 128x128 C-tile, 4 waves (64x64 quadrant each, 4x4 16x16x32 bf16
// fragments). BK=128 -> only 6 K-steps for K=768 (R2: BK=32's 24 exposed drains
// was the R1 regression; 6 drains each covered by ~1000cy compute is the fix).
// LDS per buffer per matrix = four 128x32 sub-tiles (64B row stride: conflict-free
// ds_read_b128, linear dest for global_load_lds). 2 bufs x (A+B) = 128 KB.
// A is bf16 [M][768]. BT is bf16 [N][768] (pre-transposed).
// MODE 0: QKV. n<768 -> Qw bf16 * QSCALE; 768..831 -> K; 832..895 -> VT.
// MODE 1: proj. fp32 out + bias.
template <int MODE>
__global__ __launch_bounds__(256)
void gemm128(const unsigned short* __restrict__ A, const unsigned short* __restrict__ BT,
             const float* __restrict__ bias, void* __restrict__ C0,
             unsigned short* __restrict__ Kout, unsigned short* __restrict__ VTout)
{
    __shared__ __align__(16) unsigned short sA[2][128 * 128];   // 32 KB per buf
    __shared__ __align__(16) unsigned short sB[2][128 * 128];
    const int t = threadIdx.x, lane = t & 63, w = t >> 6;
    const int bm = blockIdx.y * 128, bn = blockIdx.x * 128;
    const int wm = (w >> 1) * 64, wn = (w & 1) * 64;

    // staging chunk map (per 128x32 sub-tile kc): chunk rg covers rows [16rg,16rg+16);
    // lane l -> row 16rg + (l>>2), k-offset (l&3)*8. LDS linear = kc*4096 + rg*512 + l*8.
    const unsigned short* Apt = &A [(size_t)(bm + (lane >> 2)) * DIMC + (lane & 3) * 8];
    const unsigned short* Bpt = &BT[(size_t)(bn + (lane >> 2)) * DIMC + (lane & 3) * 8];

    auto stage = [&](int kt, int bf) {
        const int off = kt * 128;
        #pragma unroll
        for (int kc = 0; kc < 4; ++kc) {
            #pragma unroll
            for (int g = 0; g < 2; ++g) {
                const int rg = 2 * w + g;                     // wave w: rows [32w, 32w+32)
                const size_t goff = (size_t)rg * 16 * DIMC + off + kc * 32;
                gload16(Apt + goff, &sA[bf][kc * 4096 + rg * 512]);
                gload16(Bpt + goff, &sB[bf][kc * 4096 + rg * 512]);
            }
        }
    };

    // fragment addressing: A lane holds row=lane&15, k=(lane>>4)*8..+7 (B: col)
    const int fr = lane & 15, fk = (lane >> 4) * 8;

    f32x4 acc[4][4] = {};

    stage(0, 0);
    __syncthreads();
    for (int kt = 0; kt < DIMC / 128; ++kt) {
        const int buf = kt & 1;
        if (kt + 1 < DIMC / 128) stage(kt + 1, buf ^ 1);   // issue before compute
        #pragma unroll
        for (int kc = 0; kc < 4; ++kc) {
            bf16x8 af[4], bq[4];
            #pragma unroll
            for (int i = 0; i < 4; ++i)
                af[i] = *(const bf16x8*)&sA[buf][kc * 4096 + (wm + i * 16 + fr) * 32 + fk];
            #pragma unroll
            for (int j = 0; j < 4; ++j)
                bq[j] = *(const bf16x8*)&sB[buf][kc * 4096 + (wn + j * 16 + fr) * 32 + fk];
            #pragma unroll
            for (int i = 0; i < 4; ++i)
                #pragma unroll
                for (int j = 0; j < 4; ++j)
                    acc[i][j] = __builtin_amdgcn_mfma_f32_16x16x32_bf16(af[i], bq[j], acc[i][j], 0, 0, 0);
        }
        __syncthreads();   // drains this iter's prefetch AFTER ~1000cy of compute covered it
    }

    // C/D 16x16 layout: col = lane&15, row = (lane>>4)*4 + reg
    const int cn = lane & 15, cm = (lane >> 4) * 4;
    #pragma unroll
    for (int j = 0; j < 4; ++j) {
        const int n = bn + wn + j * 16 + cn;
        #pragma unroll
        for (int i = 0; i < 4; ++i) {
            #pragma unroll
            for (int r = 0; r < 4; ++r) {
                const int m = bm + wm + i * 16 + cm + r;
                float val = acc[i][j][r];
                if (MODE == 0) {
                    if (n < DIMC) {
                        ((unsigned short*)C0)[(size_t)m * DIMC + n] = f2bf(val * QSCALE);
                    } else {
                        const int c2 = n - DIMC;
                        if (c2 < HD) Kout[(size_t)m * HD + c2] = f2bf(val);
                        else {
                            const int bbk = m >> 11, tok = m & (SEQ - 1);
                            VTout[(size_t)bbk * HD * SEQ + (size_t)(c2 - HD) * SEQ + tok] = f2bf(val);
                        }
                    }
                } else {
                    ((float*)C0)[(size_t)m * DIMC + n] = val + bias[n];
                }
            }
        }
    }
}

// ---- MFMA flash attention, R5: NO LDS staging, NO main-loop barriers.
// K+V per batch = 512 KB total -> L2-resident; every MFMA operand is already
// fragment-shaped in global memory (16B/lane contiguous), so the LDS round-trip
// (write+barrier+read) bought nothing but 32 serial vmcnt-drains [common-mistake
// #7, m169]. Each wave free-runs its 32-kt chain with per-wave s_waitcnt only;
// 12 waves/CU of unsynchronized work = the TLP this latency-bound kernel lacked.
// 1-tile register prefetch, static A/B ping-pong (rule #20: no runtime indexing).
// Structure otherwise R2-proven: 768 blocks, 4 waves kr x qc, no-max softmax,
// cvt_pk + permlane32_swap [T12], setprio around MFMA [T5].
__global__ __launch_bounds__(256, 3)
void flash_kernel(const unsigned short* __restrict__ Qw, const unsigned short* __restrict__ Kw,
                  const unsigned short* __restrict__ VTw, unsigned short* __restrict__ Ob)
{
    const int qblk = blockIdx.x, h = blockIdx.y, b = blockIdx.z;
    const int tid = threadIdx.x, w = tid >> 6, lane = tid & 63;
    const int l31 = lane & 31, hi = lane >> 5;
    const int kr = w >> 1, qc = w & 1;

    __shared__ float scratch[4][1024];   // epilogue O-combine (16 KB)
    __shared__ float sL[4][32];
    __shared__ float sLi[2][32];

    const size_t qrow = (size_t)(b * SEQ + qblk * 64 + qc * 32 + l31);
    bf16x8 qf[4];
    #pragma unroll
    for (int s = 0; s < 4; ++s)
        qf[s] = *(const bf16x8*)&Qw[qrow * DIMC + h * HD + s * 16 + hi * 8];

    f32x16 oacc0 = {}, oacc1 = {};
    float lsum = 0.0f;

    // Fragment-direct global bases.
    // K (QK A-operand): lane (l31,hi) -> K[b][tok=kt*64+kr*32+l31][d=s*16+hi*8..+8]
    const unsigned short* Kbase = &Kw[((size_t)b * SEQ + kr * 32 + l31) * HD + hi * 8];
    // V (PV B-operand): lane -> VT[b][d=l31(+32)][tok=kt*64+kr*32+s*16+hi*8..+8]
    const unsigned short* V0b = &VTw[(size_t)b * HD * SEQ + (size_t)l31 * SEQ + kr * 32 + hi * 8];
    const unsigned short* V1b = V0b + (size_t)32 * SEQ;

    bf16x8 kA[4], kB[4], v0A[2], v1A[2], v0B[2], v1B[2];
    auto loadT = [&](int kt, bf16x8* kf, bf16x8* v0, bf16x8* v1) {
        const unsigned short* kp = Kbase + (size_t)kt * 64 * HD;
        kf[0] = *(const bf16x8*)&kp[0];
        kf[1] = *(const bf16x8*)&kp[16];
        kf[2] = *(const bf16x8*)&kp[32];
        kf[3] = *(const bf16x8*)&kp[48];
        const unsigned short* vp0 = V0b + kt * 64;
        const unsigned short* vp1 = V1b + kt * 64;
        v0[0] = *(const bf16x8*)&vp0[0];  v0[1] = *(const bf16x8*)&vp0[16];
        v1[0] = *(const bf16x8*)&vp1[0];  v1[1] = *(const bf16x8*)&vp1[16];
    };

    auto step = [&](const bf16x8* kf, const bf16x8* v0s, const bf16x8* v1s) {
        // S^T = K·Q^T : 4 chained k-steps over d
        f32x16 st = {};
        __builtin_amdgcn_s_setprio(1);
        #pragma unroll
        for (int s = 0; s < 4; ++s)
            st = __builtin_amdgcn_mfma_f32_32x32x16_bf16(kf[s], qf[s], st, 0, 0, 0);
        __builtin_amdgcn_s_setprio(0);

        // p = exp2(s) (scale*log2e folded into Q); pack pairs (1 op each).
        // C rows: key = (r&3)+8*(r>>2)+4*hi -> pg[g] = keys 8g+4hi+{0..3} for q=l31
        uint2 pg[4];
        #pragma unroll
        for (int g = 0; g < 4; ++g) {
            float p0 = exp2f_fast(st[g * 4 + 0]);
            float p1 = exp2f_fast(st[g * 4 + 1]);
            float p2 = exp2f_fast(st[g * 4 + 2]);
            float p3 = exp2f_fast(st[g * 4 + 3]);
            lsum += (p0 + p1) + (p2 + p3);
            pg[g].x = cvtpk_bf16(p0, p1);
            pg[g].y = cvtpk_bf16(p2, p3);
        }

        // C-layout -> A-layout via v_permlane32_swap_b32 (both halves in 1 op); PV.
        #pragma unroll
        for (int s = 0; s < 2; ++s) {
            unsigned int ax = pg[2 * s].x, bx = pg[2 * s + 1].x;
            unsigned int ay = pg[2 * s].y, by = pg[2 * s + 1].y;
            asm("v_permlane32_swap_b32 %0, %1" : "+v"(ax), "+v"(bx));
            asm("v_permlane32_swap_b32 %0, %1" : "+v"(ay), "+v"(by));
            union { uint4 u4; bf16x8 v; } pa;
            pa.u4.x = ax;   // lo: own pg[2s]     | hi: partner pg[2s+1]
            pa.u4.y = ay;
            pa.u4.z = bx;   // lo: partner pg[2s] | hi: own pg[2s+1]
            pa.u4.w = by;
            __builtin_amdgcn_s_setprio(1);
            oacc0 = __builtin_amdgcn_mfma_f32_32x32x16_bf16(pa.v, v0s[s], oacc0, 0, 0, 0);
            oacc1 = __builtin_amdgcn_mfma_f32_32x32x16_bf16(pa.v, v1s[s], oacc1, 0, 0, 0);
            __builtin_amdgcn_s_setprio(0);
        }
    };

    loadT(0, kA, v0A, v1A);
    for (int kt = 0; kt < SEQ / 64; kt += 2) {
        loadT(kt + 1, kB, v0B, v1B);          // issue; covered by step A
        step(kA, v0A, v1A);
        if (kt + 2 < SEQ / 64) loadT(kt + 2, kA, v0A, v1A);
        step(kB, v0B, v1B);
    }

    // ---- epilogue: combine key halves, divide by l, store ----
    lsum += __shfl_xor(lsum, 32);
    if (lane < 32) sL[w][l31] = lsum;

    {
        int rid = qc * 2 + (1 - kr);
        float* rg = &scratch[rid][0];
        f32x16 give = kr ? oacc0 : oacc1;
        #pragma unroll
        for (int r = 0; r < 16; ++r) rg[r * 64 + lane] = give[r];
    }
    __syncthreads();

    f32x16 own = kr ? oacc1 : oacc0;
    {
        const float* rg = &scratch[qc * 2 + kr][0];
        #pragma unroll
        for (int r = 0; r < 16; ++r) own[r] += rg[r * 64 + lane];
    }
    if (kr == 0 && lane < 32)
        sLi[qc][l31] = 1.0f / (sL[qc][l31] + sL[qc + 2][l31]);
    __syncthreads();

    #pragma unroll
    for (int r = 0; r < 16; ++r) {
        int rq = (r & 3) + 8 * (r >> 2) + 4 * hi;
        float iv = sLi[qc][rq];
        size_t row = (size_t)(b * SEQ + qblk * 64 + qc * 32 + rq);
        Ob[row * DIMC + h * HD + kr * 32 + l31] = f2bf(own[r] * iv);
    }
}

extern "C" void kernel_launch(void* const* d_in, const int* in_sizes, int n_in,
                              void* d_out, int out_size, void* d_ws, size_t ws_size,
                              hipStream_t stream)
{
    const float* x     = (const float*)d_in[0];
    const float* Wq    = (const float*)d_in[1];
    const float* Wkv   = (const float*)d_in[2];
    const float* Wproj = (const float*)d_in[3];
    const float* bproj = (const float*)d_in[4];

    const int M = BATCH * SEQ;               // 4096
    unsigned short* WqT  = (unsigned short*)d_ws;           // 768*768   } contiguous
    unsigned short* WkvT = WqT  + DIMC * DIMC;              // 128*768   } [896][768]
    unsigned short* WprT = WkvT + 2 * HD * DIMC;            // 768*768
    unsigned short* Qw   = WprT + DIMC * DIMC;              // 4096*768 (pre-scaled)
    unsigned short* Kw   = Qw   + (size_t)M * DIMC;         // 4096*64
    unsigned short* VTw  = Kw   + (size_t)M * HD;           // 2*64*2048
    unsigned short* Ob   = VTw  + (size_t)BATCH * HD * SEQ; // 4096*768
    unsigned short* xb   = Ob;   // x bf16 aliases Ob: dead before flash writes Ob

    // 1) weight transposes (1248 blocks) + x->bf16 (1536 blocks)
    prep<<<1248 + 1536, 256, 0, stream>>>(Wq, Wkv, Wproj, x, WqT, WkvT, WprT, xb);
    // 2) fused QKV: 7 x 32 = 224 blocks (N=896)
    gemm128<0><<<dim3(7, M / 128), 256, 0, stream>>>(xb, WqT, nullptr, Qw, Kw, VTw);
    // 3) flash attention -> Ob (768 blocks: 64 q-rows/block)
    flash_kernel<<<dim3(SEQ / 64, HEADS, BATCH), 256, 0, stream>>>(Qw, Kw, VTw, Ob);
    // 4) proj: 6 x 32 = 192 blocks (N=768)
    gemm128<1><<<dim3(6, M / 128), 256, 0, stream>>>(Ob, WprT, bproj, d_out, nullptr, nullptr);
}

// Round 8
// 148.802 us; speedup vs baseline: 1.3634x; 1.3634x over previous
//
#include <hip/hip_runtime.h>

// B=2, N=2048, DIM=768, HEADS=12, HD=64, SCALE=1/8
#define BATCH 2
#define SEQ   2048
#define DIMC  768
#define HEADS 12
#define HD    64
// Q prescale = attention scale (1/8) * log2(e); flash uses exp2 (v_exp_f32 native)
#define QSCALE 0.1803368801111204f

typedef short bf16x8 __attribute__((ext_vector_type(8)));
typedef float f32x4  __attribute__((ext_vector_type(4)));
typedef float f32x16 __attribute__((ext_vector_type(16)));

__device__ __forceinline__ unsigned short f2bf(float f) {
    union { float f; unsigned int u; } a; a.f = f;
    unsigned int r = a.u + 0x7fffu + ((a.u >> 16) & 1u);
    return (unsigned short)(r >> 16);
}
__device__ __forceinline__ unsigned int pack2bf(float lo, float hi) {
    union { float f; unsigned int u; } a, b; a.f = lo; b.f = hi;
    return __builtin_amdgcn_perm(b.u + 0x8000u, a.u + 0x8000u, 0x07060302);
}
// packed f32x2 -> bf16x2 in ONE VALU op (RNE). No builtin on gfx950 (m240): inline asm.
__device__ __forceinline__ unsigned int cvtpk_bf16(float lo, float hi) {
    unsigned int r;
    asm("v_cvt_pk_bf16_f32 %0, %1, %2" : "=v"(r) : "v"(lo), "v"(hi));
    return r;
}
// 2^x via the native v_exp_f32 (avoid __exp2f: collides with glibc math.h on this toolchain)
__device__ __forceinline__ float exp2f_fast(float x) { return __builtin_amdgcn_exp2f(x); }

// async global->LDS, 16B per lane. LDS dest is wave-uniform base + lane*16.
__device__ __forceinline__ void gload16(const unsigned short* g, unsigned short* l) {
    __builtin_amdgcn_global_load_lds(
        (const __attribute__((address_space(1))) unsigned int*)g,
        (__attribute__((address_space(3))) unsigned int*)l, 16, 0, 0);
}

// ---- prep: weight transposes + x fp32->bf16 (R4-exact, known-good). ----
// blocks [0,1248): W [768][N] fp32 -> WT [N][768] bf16 via 32x32 LDS tiles.
// blocks [1248,2784): x -> xb, 2048 elems/block, vectorized.
__global__ void prep(const float* __restrict__ Wq, const float* __restrict__ Wkv,
                     const float* __restrict__ Wproj, const float* __restrict__ x,
                     unsigned short* __restrict__ WqT, unsigned short* __restrict__ WkvT,
                     unsigned short* __restrict__ WprT, unsigned short* __restrict__ xb)
{
    const int bid = blockIdx.x, t = threadIdx.x;
    if (bid >= 1248) {
        const size_t base = (size_t)(bid - 1248) * 2048 + (size_t)t * 8;
        float4 v0 = *(const float4*)&x[base];
        float4 v1 = *(const float4*)&x[base + 4];
        uint4 o = { pack2bf(v0.x, v0.y), pack2bf(v0.z, v0.w),
                    pack2bf(v1.x, v1.y), pack2bf(v1.z, v1.w) };
        *(uint4*)&xb[base] = o;
        return;
    }
    __shared__ float sT[32][33];
    const float* W; unsigned short* WT; int N, tb;
    if (bid < 576)      { W = Wq;    WT = WqT;  N = DIMC;   tb = bid; }
    else if (bid < 672) { W = Wkv;   WT = WkvT; N = 2 * HD; tb = bid - 576; }
    else                { W = Wproj; WT = WprT; N = DIMC;   tb = bid - 672; }
    const int tilesN = N / 32;
    const int k0 = (tb / tilesN) * 32, n0 = (tb - (tb / tilesN) * tilesN) * 32;
    const int r = t >> 3, c4 = (t & 7) * 4;
    float4 v = *(const float4*)&W[(size_t)(k0 + r) * N + n0 + c4];
    sT[c4 + 0][r] = v.x; sT[c4 + 1][r] = v.y; sT[c4 + 2][r] = v.z; sT[c4 + 3][r] = v.w;
    __syncthreads();
    ushort4 o = { f2bf(sT[r][c4]), f2bf(sT[r][c4 + 1]), f2bf(sT[r][c4 + 2]), f2bf(sT[r][c4 + 3]) };
    *(ushort4*)&WT[(size_t)(n0 + r) * 768 + k0 + c4] = o;
}

// ---- GEMM (R6 gemm_phase geometry, STANDALONE for bisect validation):
// 64x128 C-tile, 4 waves (32x64 each: 2x4 16x16x32 fragments), BK=64 dbuf.
// LDS: sA[2][4096]sh 16KB + sB[2][8192]sh 32KB = 48KB -> up to 3 blocks/CU
// co-resident (448/384-block grids ~2/CU average: more drain-hiding TLP than
// gemm128's 1/CU). MFMA k-slice order (0,32,...,736) identical to gemm128 ->
// bitwise-identical outputs; absmax must be exactly 0.001953125 if correct.
// MODE 0: QKV. n<768 -> Qw bf16*QSCALE; 768..831 -> K; 832..895 -> VT.
// MODE 1: proj. fp32 out + bias.
template <int MODE>
__global__ __launch_bounds__(256)
void gemm64(const unsigned short* __restrict__ A, const unsigned short* __restrict__ BT,
            const float* __restrict__ bias, void* __restrict__ C0,
            unsigned short* __restrict__ Kout, unsigned short* __restrict__ VTout)
{
    __shared__ __align__(16) unsigned short sA[2][4096];
    __shared__ __align__(16) unsigned short sB[2][8192];
    const int t = threadIdx.x, lane = t & 63, w = t >> 6;
    const int bm = blockIdx.y * 64, bn = blockIdx.x * 128;
    const int wm = (w >> 1) * 32, wn = (w & 1) * 64;
    const int cr = lane >> 2, ck = (lane & 3) * 8;   // 1KB chunk: 16 rows x 32 k

    auto stage = [&](int kt, int bf) {
        #pragma unroll
        for (int q = 0; q < 2; ++q) {                 // A: 8 chunks, wave w -> 2w,2w+1
            const int c = 2 * w + q, kc = c >> 2, rg = c & 3;
            gload16(&A[(size_t)(bm + rg * 16 + cr) * DIMC + kt * 64 + kc * 32 + ck],
                    &sA[bf][kc * 2048 + rg * 512]);
        }
        #pragma unroll
        for (int q = 0; q < 4; ++q) {                 // B: 16 chunks, wave w -> 4w..4w+3
            const int c = 4 * w + q, kc = c >> 3, rg = c & 7;
            gload16(&BT[(size_t)(bn + rg * 16 + cr) * DIMC + kt * 64 + kc * 32 + ck],
                    &sB[bf][kc * 4096 + rg * 512]);
        }
    };

    // fragment addressing: A lane holds row=lane&15, k=(lane>>4)*8..+7 (B: col)
    const int fr = lane & 15, fk = (lane >> 4) * 8;
    f32x4 acc[2][4] = {};

    stage(0, 0);
    __syncthreads();
    for (int kt = 0; kt < DIMC / 64; ++kt) {
        const int buf = kt & 1;
        if (kt + 1 < DIMC / 64) stage(kt + 1, buf ^ 1);   // issue before compute
        #pragma unroll
        for (int kc = 0; kc < 2; ++kc) {
            bf16x8 af[2], bq[4];
            #pragma unroll
            for (int i = 0; i < 2; ++i)
                af[i] = *(const bf16x8*)&sA[buf][kc * 2048 + (wm + i * 16 + fr) * 32 + fk];
            #pragma unroll
            for (int j = 0; j < 4; ++j)
                bq[j] = *(const bf16x8*)&sB[buf][kc * 4096 + (wn + j * 16 + fr) * 32 + fk];
            #pragma unroll
            for (int i = 0; i < 2; ++i)
                #pragma unroll
                for (int j = 0; j < 4; ++j)
                    acc[i][j] = __builtin_amdgcn_mfma_f32_16x16x32_bf16(af[i], bq[j], acc[i][j], 0, 0, 0);
        }
        __syncthreads();   // drains this iter's prefetch after compute covered it
    }

    // C/D 16x16 layout: col = lane&15, row = (lane>>4)*4 + reg
    const int cn = lane & 15, cm = (lane >> 4) * 4;
    #pragma unroll
    for (int j = 0; j < 4; ++j) {
        const int n = bn + wn + j * 16 + cn;
        #pragma unroll
        for (int i = 0; i < 2; ++i) {
            #pragma unroll
            for (int r = 0; r < 4; ++r) {
                const int m = bm + wm + i * 16 + cm + r;
                float val = acc[i][j][r];
                if (MODE == 0) {
                    if (n < DIMC) {
                        ((unsigned short*)C0)[(size_t)m * DIMC + n] = f2bf(val * QSCALE);
                    } else {
                        const int c2 = n - DIMC;
                        if (c2 < HD) Kout[(size_t)m * HD + c2] = f2bf(val);
                        else {
                            const int bbk = m >> 11, tok = m & (SEQ - 1);
                            VTout[(size_t)bbk * HD * SEQ + (size_t)(c2 - HD) * SEQ + tok] = f2bf(val);
                        }
                    }
                } else {
                    ((float*)C0)[(size_t)m * DIMC + n] = val + bias[n];
                }
            }
        }
    }
}

// ---- MFMA flash attention: R4-exact (48.6us, known-good). 768 blocks, 4 waves
// kr x qc, 64 q/block, no-max softmax exact via shift-invariance, 2-deep register
// staging pipeline, cvt_pk + permlane32_swap [T12], setprio around MFMA [T5].
__global__ __launch_bounds__(256)
void flash_kernel(const unsigned short* __restrict__ Qw, const unsigned short* __restrict__ Kw,
                  const unsigned short* __restrict__ VTw, unsigned short* __restrict__ Ob)
{
    const int qblk = blockIdx.x, h = blockIdx.y, b = blockIdx.z;
    const int tid = threadIdx.x, w = tid >> 6, lane = tid & 63;
    const int l31 = lane & 31, hi = lane >> 5;
    const int kr = w >> 1, qc = w & 1;

    __shared__ __align__(16) unsigned short sK [2][64][72];
    __shared__ __align__(16) unsigned short sVT[2][64][72];
    __shared__ float sL[4][32];
    __shared__ float sLi[2][32];

    const size_t qrow = (size_t)(b * SEQ + qblk * 64 + qc * 32 + l31);
    bf16x8 qf[4];
    #pragma unroll
    for (int s = 0; s < 4; ++s)
        qf[s] = *(const bf16x8*)&Qw[qrow * DIMC + h * HD + s * 16 + hi * 8];

    f32x16 oacc0 = {}, oacc1 = {};
    float lsum = 0.0f;

    const int r_st = tid >> 2, c_st = (tid & 3) * 16;
    const unsigned short* Kp  = &Kw[(size_t)(b * SEQ + r_st) * HD + c_st];
    const unsigned short* VTp = &VTw[(size_t)b * HD * SEQ + (size_t)r_st * SEQ + c_st];

    bf16x8 kg0, kg1, vg0, vg1;
    auto loadKV = [&](int ti) {
        const unsigned short* ks = Kp + (size_t)ti * 64 * HD;
        const unsigned short* vs = VTp + ti * 64;
        kg0 = *(const bf16x8*)&ks[0]; kg1 = *(const bf16x8*)&ks[8];
        vg0 = *(const bf16x8*)&vs[0]; vg1 = *(const bf16x8*)&vs[8];
    };
    auto writeKV = [&](int bf) {
        *(bf16x8*)&sK[bf][r_st][c_st]      = kg0;
        *(bf16x8*)&sK[bf][r_st][c_st + 8]  = kg1;
        *(bf16x8*)&sVT[bf][r_st][c_st]     = vg0;
        *(bf16x8*)&sVT[bf][r_st][c_st + 8] = vg1;
    };

    loadKV(0); writeKV(0); loadKV(1);
    __syncthreads();

    for (int kt = 0; kt < SEQ / 64; ++kt) {
        const int buf = kt & 1;
        if (kt + 1 < SEQ / 64) {
            writeKV(buf ^ 1);                          // tile kt+1 (regs from last iter)
            loadKV(kt + 2 < SEQ / 64 ? kt + 2 : SEQ / 64 - 1);
        }

        // S^T = K·Q^T : A=K rows kr*32+l31, 4 chained k-steps over d
        f32x16 st = {};
        __builtin_amdgcn_s_setprio(1);
        #pragma unroll
        for (int s = 0; s < 4; ++s) {
            bf16x8 ka = *(const bf16x8*)&sK[buf][kr * 32 + l31][s * 16 + hi * 8];
            st = __builtin_amdgcn_mfma_f32_32x32x16_bf16(ka, qf[s], st, 0, 0, 0);
        }
        __builtin_amdgcn_s_setprio(0);

        // p = exp2(s) (scale*log2e folded into Q); pack pairs (1 op each). C rows:
        // key = (r&3)+8*(r>>2)+4*hi -> pg[g] = keys 8g+4hi+{0..3} for q=l31
        uint2 pg[4];
        #pragma unroll
        for (int g = 0; g < 4; ++g) {
            float p0 = exp2f_fast(st[g * 4 + 0]);
            float p1 = exp2f_fast(st[g * 4 + 1]);
            float p2 = exp2f_fast(st[g * 4 + 2]);
            float p3 = exp2f_fast(st[g * 4 + 3]);
            lsum += (p0 + p1) + (p2 + p3);
            pg[g].x = cvtpk_bf16(p0, p1);
            pg[g].y = cvtpk_bf16(p2, p3);
        }

        // C-layout -> A-layout via v_permlane32_swap_b32 (both halves in 1 op); PV.
        #pragma unroll
        for (int s = 0; s < 2; ++s) {
            unsigned int ax = pg[2 * s].x, bx = pg[2 * s + 1].x;
            unsigned int ay = pg[2 * s].y, by = pg[2 * s + 1].y;
            asm("v_permlane32_swap_b32 %0, %1" : "+v"(ax), "+v"(bx));
            asm("v_permlane32_swap_b32 %0, %1" : "+v"(ay), "+v"(by));
            union { uint4 u4; bf16x8 v; } pa;
            pa.u4.x = ax;   // lo: own pg[2s]     | hi: partner pg[2s+1]
            pa.u4.y = ay;
            pa.u4.z = bx;   // lo: partner pg[2s] | hi: own pg[2s+1]
            pa.u4.w = by;
            bf16x8 vb0 = *(const bf16x8*)&sVT[buf][l31][kr * 32 + s * 16 + hi * 8];
            bf16x8 vb1 = *(const bf16x8*)&sVT[buf][32 + l31][kr * 32 + s * 16 + hi * 8];
            __builtin_amdgcn_s_setprio(1);
            oacc0 = __builtin_amdgcn_mfma_f32_32x32x16_bf16(pa.v, vb0, oacc0, 0, 0, 0);
            oacc1 = __builtin_amdgcn_mfma_f32_32x32x16_bf16(pa.v, vb1, oacc1, 0, 0, 0);
            __builtin_amdgcn_s_setprio(0);
        }
        __syncthreads();
    }

    // ---- epilogue: combine key halves, divide by l, store ----
    lsum += __shfl_xor(lsum, 32);
    if (lane < 32) sL[w][l31] = lsum;

    float* scratch = (float*)&sK[0][0][0];   // staging dead after loop
    {
        int rid = qc * 2 + (1 - kr);
        float* rg = scratch + rid * 1024;
        f32x16 give = kr ? oacc0 : oacc1;
        #pragma unroll
        for (int r = 0; r < 16; ++r) rg[r * 64 + lane] = give[r];
    }
    __syncthreads();

    f32x16 own = kr ? oacc1 : oacc0;
    {
        const float* rg = scratch + (qc * 2 + kr) * 1024;
        #pragma unroll
        for (int r = 0; r < 16; ++r) own[r] += rg[r * 64 + lane];
    }
    if (kr == 0 && lane < 32)
        sLi[qc][l31] = 1.0f / (sL[qc][l31] + sL[qc + 2][l31]);
    __syncthreads();

    #pragma unroll
    for (int r = 0; r < 16; ++r) {
        int rq = (r & 3) + 8 * (r >> 2) + 4 * hi;
        float iv = sLi[qc][rq];
        size_t row = (size_t)(b * SEQ + qblk * 64 + qc * 32 + rq);
        Ob[row * DIMC + h * HD + kr * 32 + l31] = f2bf(own[r] * iv);
    }
}

extern "C" void kernel_launch(void* const* d_in, const int* in_sizes, int n_in,
                              void* d_out, int out_size, void* d_ws, size_t ws_size,
                              hipStream_t stream)
{
    const float* x     = (const float*)d_in[0];
    const float* Wq    = (const float*)d_in[1];
    const float* Wkv   = (const float*)d_in[2];
    const float* Wproj = (const float*)d_in[3];
    const float* bproj = (const float*)d_in[4];

    const int M = BATCH * SEQ;               // 4096
    unsigned short* WqT  = (unsigned short*)d_ws;           // 768*768   } contiguous
    unsigned short* WkvT = WqT  + DIMC * DIMC;              // 128*768   } [896][768]
    unsigned short* WprT = WkvT + 2 * HD * DIMC;            // 768*768
    unsigned short* Qw   = WprT + DIMC * DIMC;              // 4096*768 (pre-scaled)
    unsigned short* Kw   = Qw   + (size_t)M * DIMC;         // 4096*64
    unsigned short* VTw  = Kw   + (size_t)M * HD;           // 2*64*2048
    unsigned short* Ob   = VTw  + (size_t)BATCH * HD * SEQ; // 4096*768
    unsigned short* xb   = Ob;   // x bf16 aliases Ob: safe across DISPATCH
                                 // boundaries (proven R4); dead before flash.

    // 1) weight transposes (1248 blocks) + x->bf16 (1536 blocks)
    prep<<<1248 + 1536, 256, 0, stream>>>(Wq, Wkv, Wproj, x, WqT, WkvT, WprT, xb);
    // 2) fused QKV: 7 x 64 = 448 blocks (N=896, 64-row M-tiles)
    gemm64<0><<<dim3(7, M / 64), 256, 0, stream>>>(xb, WqT, nullptr, Qw, Kw, VTw);
    // 3) flash attention -> Ob (768 blocks: 64 q-rows/block)
    flash_kernel<<<dim3(SEQ / 64, HEADS, BATCH), 256, 0, stream>>>(Qw, Kw, VTw, Ob);
    // 4) proj: 6 x 64 = 384 blocks
    gemm64<1><<<dim3(6, M / 64), 256, 0, stream>>>(Ob, WprT, bproj, d_out, nullptr, nullptr);
}